// Round 17
// baseline (90.897 us; speedup 1.0000x reference)
//
#include <hip/hip_runtime.h>
#include <math.h>

// Fused SIFT-like pipeline:
//   Sobel(3x3, pad1) -> project onto 8 orientations -> argmax -> magnitude
//   into winning bin -> depthwise 4x4 ones conv (pad2) => out (8,8,1025,1025)
//
// v17 = v14 (84.4us, passing: octant argmax + bisector fallback, batch==XCD
// swizzle, DPP horizontal sums, 1 hist col/lane) with ONE geometry change:
// the block's 4 waves cover 4 ADJACENT 61-col strips of the SAME 16 rows
// (block tile 244x16 instead of 61x64). Near-lockstep waves write ~976B
// contiguous per (plane,row) instead of 244B -> write-burst locality test.
// Per-lane math/masks/ring BYTE-IDENTICAL to v14.
//
// Block = 256 threads (4 waves). Wave wv: out cols j0blk+61wv .. +60, rows
// r0..r0+15. Lane l owns hist col j0-2+l; out col c = hist cols c..c+3 via
// DPP wave_shl:1 chains (lanes 61..63 feed only). launch_bounds(256,4).

#define TWC 61              // out cols per wave strip
#define BCW 244             // out cols per block (4 strips)
#define WTH 16              // out rows per block (all waves)
#define XR  21              // staged x rows (r0-3 .. r0+17)
#define XC  250             // staged x cols (j0blk-3 .. j0blk+246)
#define PLANE 1050625       // 1025*1025
#define NCT 5               // col tiles (5*244 = 1220 >= 1025)
#define NRT 65              // row tiles (65*16 = 1040 >= 1025)

// DPP wave_shl:1 (0x130): lane i <- lane i+1, zero-fill (== shfl_down 1)
__device__ __forceinline__ float wshl1(float v) {
    return __int_as_float(
        __builtin_amdgcn_update_dpp(0, __float_as_int(v), 0x130, 0xf, 0xf, true));
}

__global__ __launch_bounds__(256, 4)
void sift_fused(const float* __restrict__ x,
                const float* __restrict__ ow,
                float* __restrict__ out)
{
    __shared__ float sx[XR * XC];          // 21,000 B

    const int tid  = threadIdx.x;
    const int lane = tid & 63;
    const int wv   = tid >> 6;

    // XCD-aware remap: batch == XCD (2600 blocks, 2600%8==0, bijective)
    const int flat = blockIdx.x + NCT * (blockIdx.y + NRT * blockIdx.z);
    const int bb = flat & 7;
    const int t  = flat >> 3;              // 0..324
    const int bx = t % NCT;
    const int by = t / NCT;
    const int j0blk = bx * BCW;
    const int r0 = by * WTH;

    // ---- stage x tile into LDS (zero-padded at image borders) ----
    const float* xb = x + (size_t)bb * 1024 * 1024;
    for (int p = tid; p < XR * XC; p += 256) {
        int r = p / XC, c = p - r * XC;
        int gr = r0 - 3 + r, gc = j0blk - 3 + c;
        float v = 0.0f;
        if ((unsigned)gr < 1024u && (unsigned)gc < 1024u)
            v = xb[(size_t)gr * 1024 + gc];
        sx[p] = v;
    }
    __syncthreads();

    const int rbase = r0;                      // same rows for all waves
    if (rbase > 1024) return;                  // uniform; no barriers after

    const int j0 = j0blk + TWC * wv;           // this wave's strip origin

    // orientation weights (uniform loads; used by exact fallback path)
    float wcn[8], wsn[8];
    #pragma unroll
    for (int o = 0; o < 8; ++o) { wcn[o] = ow[2*o]; wsn[o] = ow[2*o+1]; }

    const int gcol = j0 - 2 + lane;            // hist column this lane owns
    const bool colok = (unsigned)gcol < 1024u;
    const int gj = j0 + lane;                  // output column this lane stores
    const bool canstore = (lane < TWC) && (gj <= 1024);

    // 8 uniform per-channel plane base pointers
    float* po[8];
    #pragma unroll
    for (int o = 0; o < 8; ++o) po[o] = out + (size_t)(bb * 8 + o) * PLANE;

    // x row cursor: staged row 0, this wave's strip + lane (3 cols/lane)
    const float* px = sx + TWC * wv + lane;
    int hrow = rbase - 2;                      // global hist row of current step
    int orow = rbase;                          // global out row of next FIN
    int vo   = rbase * 1025 + gj;              // element offset within a plane

    // register state: d/w row-sum rings (slot = xrow & 3), contrib ping-pong,
    // pair-sum ring (slot = histrow & 3)
    float dd0, dd1, dd2, dd3, ww0, ww1, ww2, ww3;
    float cA[8], cB[8], PP0[8], PP1[8], PP2[8], PP3[8];

#define XROWLOAD(DD, WW) { \
    float n0 = px[0], n1 = px[1], n2 = px[2]; px += XC; \
    DD = n2 - n0; \
    WW = n0 + 2.0f*n1 + n2; \
}

// One hist row: load x row j+2 -> (DB,WB); Sobel from rings; magnitude;
// argmax: octant fast path, wave-uniform fallback to bit-exact
// projection+tournament near bisectors; one-hot contrib CC;
// pair sum PC = CP + CC; optional FIN of out row j-3.
#define HSTEP(DT, DM, DB, WT, WB, CP, CC, PR, PC, DOP, DOFIN) { \
    XROWLOAD(DB, WB) \
    float gx = DT + 2.0f*DM + DB; \
    float gy = WB - WT; \
    float msq = gx*gx + gy*gy; \
    float m = (colok && (unsigned)hrow < 1024u) \
                ? __builtin_amdgcn_sqrtf(msq) : 0.0f; \
    hrow++; \
    float ax_ = fabsf(gx), ay_ = fabsf(gy); \
    bool risky_ = fminf(fminf(ax_, ay_), fabsf(ay_ - ax_)) \
                    < 6.103515625e-5f * (ax_ + ay_); \
    int idx; \
    if (__any(risky_)) { \
        float pj0 = gx*wcn[0] + gy*wsn[0]; \
        float pj1 = gx*wcn[1] + gy*wsn[1]; \
        float pj2 = gx*wcn[2] + gy*wsn[2]; \
        float pj3 = gx*wcn[3] + gy*wsn[3]; \
        float pj4 = gx*wcn[4] + gy*wsn[4]; \
        float pj5 = gx*wcn[5] + gy*wsn[5]; \
        float pj6 = gx*wcn[6] + gy*wsn[6]; \
        float pj7 = gx*wcn[7] + gy*wsn[7]; \
        bool g01 = pj1 > pj0; float b01 = g01 ? pj1 : pj0; int i01 = g01 ? 1 : 0; \
        bool g23 = pj3 > pj2; float b23 = g23 ? pj3 : pj2; int i23 = g23 ? 3 : 2; \
        bool g45 = pj5 > pj4; float b45 = g45 ? pj5 : pj4; int i45 = g45 ? 5 : 4; \
        bool g67 = pj7 > pj6; float b67 = g67 ? pj7 : pj6; int i67 = g67 ? 7 : 6; \
        bool gA = b23 > b01; float bA = gA ? b23 : b01; int iA = gA ? i23 : i01; \
        bool gB = b67 > b45; float bB = gB ? b67 : b45; int iB = gB ? i67 : i45; \
        idx = (bB > bA) ? iB : iA; \
    } else { \
        bool a_ = gy < 0.0f, b_ = gx < 0.0f; \
        int c_ = (ay_ >= ax_) ? 1 : 0; \
        idx = b_ ? (a_ ? (4 + c_) : (3 - c_)) \
                 : (a_ ? (7 - c_) : c_); \
    } \
    _Pragma("unroll") \
    for (int o = 0; o < 8; ++o) CC[o] = (idx == o) ? m : 0.0f; \
    if (DOP) { \
        _Pragma("unroll") \
        for (int o = 0; o < 8; ++o) PC[o] = CP[o] + CC[o]; \
    } \
    if (DOFIN) { \
        bool ok = canstore && (orow <= 1024); \
        _Pragma("unroll") \
        for (int o = 0; o < 8; ++o) { \
            float v = PR[o] + PC[o]; \
            v += wshl1(v);                 /* + lane l+1            */ \
            v += wshl1(wshl1(v));          /* + lanes l+2, l+3      */ \
            if (ok) po[o][vo] = v; \
        } \
        vo += 1025; orow++; \
    } \
}

    // prologue: x rows 0,1 then hist rows j=0..2 (no FIN yet)
    XROWLOAD(dd0, ww0)
    XROWLOAD(dd1, ww1)
    HSTEP(dd0, dd1, dd2, ww0, ww2, cA, cB, PP0, PP0, 0, 0)   // j=0 (P_0 unused)
    HSTEP(dd1, dd2, dd3, ww1, ww3, cB, cA, PP0, PP1, 1, 0)   // j=1
    HSTEP(dd2, dd3, dd0, ww2, ww0, cA, cB, PP0, PP2, 1, 0)   // j=2

    // steady state: j = 3..18, FIN t = j-3 = 0..15
    #pragma unroll 1
    for (int it = 0; it < 4; ++it) {
        HSTEP(dd3, dd0, dd1, ww3, ww1, cB, cA, PP1, PP3, 1, 1)   // j%4==3
        HSTEP(dd0, dd1, dd2, ww0, ww2, cA, cB, PP2, PP0, 1, 1)   // j%4==0
        HSTEP(dd1, dd2, dd3, ww1, ww3, cB, cA, PP3, PP1, 1, 1)   // j%4==1
        HSTEP(dd2, dd3, dd0, ww2, ww0, cA, cB, PP0, PP2, 1, 1)   // j%4==2
    }

#undef HSTEP
#undef XROWLOAD
}

extern "C" void kernel_launch(void* const* d_in, const int* in_sizes, int n_in,
                              void* d_out, int out_size, void* d_ws, size_t ws_size,
                              hipStream_t stream)
{
    (void)in_sizes; (void)n_in; (void)d_ws; (void)ws_size; (void)out_size;
    const float* x  = (const float*)d_in[0];
    const float* ow = (const float*)d_in[2];   // orient_w (10,2): rows 0..7 = [cos, sin]
    float* out = (float*)d_out;

    dim3 grid(NCT, NRT, 8);                    // 2600 blocks
    sift_fused<<<grid, 256, 0, stream>>>(x, ow, out);
}

// Round 18
// 88.111 us; speedup vs baseline: 1.0316x; 1.0316x over previous
//
#include <hip/hip_runtime.h>
#include <math.h>

// Fused SIFT-like pipeline:
//   Sobel(3x3, pad1) -> project onto 8 orientations -> argmax -> magnitude
//   into winning bin -> depthwise 4x4 ones conv (pad2) => out (8,8,1025,1025)
//
// v18 = v14 (84.4us, passing) with ONE change: paired-row stores. Even-row
// FIN buffers its 8 channel values in VGPRs; odd-row FIN stores BOTH rows
// per plane back-to-back (same/adjacent DRAM page) -> halves plane-stream
// switch cadence. Values bit-identical; store ORDER is the only variable.
//
// Block = 256 threads (4 waves), tile 61 out cols x 64 out rows; wave owns
// 16 rows (rbase even -> FIN parity static). Lane l owns hist col j0-2+l;
// out col c = hist cols c..c+3 via DPP wave_shl:1 chains. batch==XCD
// swizzle. launch_bounds(256,4).

#define TWC 61              // out cols per tile
#define WTH 16              // out rows per wave
#define WPB 4               // waves per block
#define BTH (WPB*WTH)       // 64 out rows per block
#define XC 66               // staged x cols (j0-3 .. j0+62)
#define XR (BTH+5)          // 69 staged x rows
#define PLANE 1050625       // 1025*1025
#define NCT 17              // col tiles
#define NRT 17              // row tiles

// DPP wave_shl:1 (0x130): lane i <- lane i+1, zero-fill (== shfl_down 1)
__device__ __forceinline__ float wshl1(float v) {
    return __int_as_float(
        __builtin_amdgcn_update_dpp(0, __float_as_int(v), 0x130, 0xf, 0xf, true));
}

__global__ __launch_bounds__(256, 4)
void sift_fused(const float* __restrict__ x,
                const float* __restrict__ ow,
                float* __restrict__ out)
{
    __shared__ float sx[XR * XC];

    const int tid  = threadIdx.x;
    const int lane = tid & 63;
    const int wv   = tid >> 6;

    // XCD-aware remap: batch == XCD (8 batches, 8 XCDs, bijective)
    const int flat = blockIdx.x + NCT * (blockIdx.y + NRT * blockIdx.z);
    const int bb = flat & 7;
    const int t  = flat >> 3;
    const int bx = t % NCT;
    const int by = t / NCT;
    const int j0 = bx * TWC;
    const int r0 = by * BTH;

    // ---- stage x tile into LDS (zero-padded at image borders) ----
    const float* xb = x + (size_t)bb * 1024 * 1024;
    for (int p = tid; p < XR * XC; p += 256) {
        int r = p / XC, c = p - r * XC;
        int gr = r0 - 3 + r, gc = j0 - 3 + c;
        float v = 0.0f;
        if ((unsigned)gr < 1024u && (unsigned)gc < 1024u)
            v = xb[(size_t)gr * 1024 + gc];
        sx[p] = v;
    }
    __syncthreads();

    const int rbase = r0 + WTH * wv;           // first output row (even)
    if (rbase > 1024) return;                  // no barriers after this point

    // orientation weights (uniform loads; used by exact fallback path)
    float wcn[8], wsn[8];
    #pragma unroll
    for (int o = 0; o < 8; ++o) { wcn[o] = ow[2*o]; wsn[o] = ow[2*o+1]; }

    const int gcol = j0 - 2 + lane;            // hist column this lane owns
    const bool colok = (unsigned)gcol < 1024u;
    const int gj = j0 + lane;                  // output column this lane stores
    const bool canstore = (lane < TWC) && (gj <= 1024);

    // 8 uniform per-channel plane base pointers
    float* po[8];
    #pragma unroll
    for (int o = 0; o < 8; ++o) po[o] = out + (size_t)(bb * 8 + o) * PLANE;

    const float* px = sx + (WTH * wv) * XC + lane;  // x row cursor (3 cols/lane)
    int hrow = rbase - 2;                      // global hist row of current step
    int orow = rbase;                          // global out row of next FIN
    int vo   = rbase * 1025 + gj;              // element offset within a plane

    // register state: d/w row-sum rings (slot = xrow & 3), contrib ping-pong,
    // pair-sum ring (slot = histrow & 3), even-row store buffer fs[8]
    float dd0, dd1, dd2, dd3, ww0, ww1, ww2, ww3;
    float cA[8], cB[8], PP0[8], PP1[8], PP2[8], PP3[8];
    float fs[8];

#define XROWLOAD(DD, WW) { \
    float n0 = px[0], n1 = px[1], n2 = px[2]; px += XC; \
    DD = n2 - n0; \
    WW = n0 + 2.0f*n1 + n2; \
}

// One hist row: load x row j+2 -> (DB,WB); Sobel from rings; magnitude;
// argmax: octant fast path, wave-uniform fallback to bit-exact
// projection+tournament near bisectors; one-hot contrib CC;
// pair sum PC = CP + CC; optional FIN of out row j-3.
// EVENK compile-time: even FIN buffers into fs[]; odd FIN stores both rows
// per plane back-to-back (rows orow-1 and orow at odd FIN time).
#define HSTEP(DT, DM, DB, WT, WB, CP, CC, PR, PC, DOP, DOFIN, EVENK) { \
    XROWLOAD(DB, WB) \
    float gx = DT + 2.0f*DM + DB; \
    float gy = WB - WT; \
    float msq = gx*gx + gy*gy; \
    float m = (colok && (unsigned)hrow < 1024u) \
                ? __builtin_amdgcn_sqrtf(msq) : 0.0f; \
    hrow++; \
    float ax_ = fabsf(gx), ay_ = fabsf(gy); \
    bool risky_ = fminf(fminf(ax_, ay_), fabsf(ay_ - ax_)) \
                    < 6.103515625e-5f * (ax_ + ay_); \
    int idx; \
    if (__any(risky_)) { \
        float pj0 = gx*wcn[0] + gy*wsn[0]; \
        float pj1 = gx*wcn[1] + gy*wsn[1]; \
        float pj2 = gx*wcn[2] + gy*wsn[2]; \
        float pj3 = gx*wcn[3] + gy*wsn[3]; \
        float pj4 = gx*wcn[4] + gy*wsn[4]; \
        float pj5 = gx*wcn[5] + gy*wsn[5]; \
        float pj6 = gx*wcn[6] + gy*wsn[6]; \
        float pj7 = gx*wcn[7] + gy*wsn[7]; \
        bool g01 = pj1 > pj0; float b01 = g01 ? pj1 : pj0; int i01 = g01 ? 1 : 0; \
        bool g23 = pj3 > pj2; float b23 = g23 ? pj3 : pj2; int i23 = g23 ? 3 : 2; \
        bool g45 = pj5 > pj4; float b45 = g45 ? pj5 : pj4; int i45 = g45 ? 5 : 4; \
        bool g67 = pj7 > pj6; float b67 = g67 ? pj7 : pj6; int i67 = g67 ? 7 : 6; \
        bool gA = b23 > b01; float bA = gA ? b23 : b01; int iA = gA ? i23 : i01; \
        bool gB = b67 > b45; float bB = gB ? b67 : b45; int iB = gB ? i67 : i45; \
        idx = (bB > bA) ? iB : iA; \
    } else { \
        bool a_ = gy < 0.0f, b_ = gx < 0.0f; \
        int c_ = (ay_ >= ax_) ? 1 : 0; \
        idx = b_ ? (a_ ? (4 + c_) : (3 - c_)) \
                 : (a_ ? (7 - c_) : c_); \
    } \
    _Pragma("unroll") \
    for (int o = 0; o < 8; ++o) CC[o] = (idx == o) ? m : 0.0f; \
    if (DOP) { \
        _Pragma("unroll") \
        for (int o = 0; o < 8; ++o) PC[o] = CP[o] + CC[o]; \
    } \
    if (DOFIN) { \
        if (EVENK) { \
            _Pragma("unroll") \
            for (int o = 0; o < 8; ++o) { \
                float v = PR[o] + PC[o]; \
                v += wshl1(v); \
                v += wshl1(wshl1(v)); \
                fs[o] = v; \
            } \
        } else { \
            bool okE = canstore && (orow - 1 <= 1024); \
            bool okO = canstore && (orow <= 1024); \
            _Pragma("unroll") \
            for (int o = 0; o < 8; ++o) { \
                float v = PR[o] + PC[o]; \
                v += wshl1(v); \
                v += wshl1(wshl1(v)); \
                if (okE) po[o][vo - 1025] = fs[o]; \
                if (okO) po[o][vo] = v; \
            } \
        } \
        vo += 1025; orow++; \
    } \
}

    // prologue: x rows 0,1 then hist rows j=0..2 (no FIN yet)
    XROWLOAD(dd0, ww0)
    XROWLOAD(dd1, ww1)
    HSTEP(dd0, dd1, dd2, ww0, ww2, cA, cB, PP0, PP0, 0, 0, 0)   // j=0
    HSTEP(dd1, dd2, dd3, ww1, ww3, cB, cA, PP0, PP1, 1, 0, 0)   // j=1
    HSTEP(dd2, dd3, dd0, ww2, ww0, cA, cB, PP0, PP2, 1, 0, 0)   // j=2

    // steady state: j = 3..18, FIN t = j-3 = 0..15 (t parity static)
    #pragma unroll 1
    for (int it = 0; it < 4; ++it) {
        HSTEP(dd3, dd0, dd1, ww3, ww1, cB, cA, PP1, PP3, 1, 1, 1)  // t even: buffer
        HSTEP(dd0, dd1, dd2, ww0, ww2, cA, cB, PP2, PP0, 1, 1, 0)  // t odd: store pair
        HSTEP(dd1, dd2, dd3, ww1, ww3, cB, cA, PP3, PP1, 1, 1, 1)  // t even
        HSTEP(dd2, dd3, dd0, ww2, ww0, cA, cB, PP0, PP2, 1, 1, 0)  // t odd
    }

#undef HSTEP
#undef XROWLOAD
}

extern "C" void kernel_launch(void* const* d_in, const int* in_sizes, int n_in,
                              void* d_out, int out_size, void* d_ws, size_t ws_size,
                              hipStream_t stream)
{
    (void)in_sizes; (void)n_in; (void)d_ws; (void)ws_size; (void)out_size;
    const float* x  = (const float*)d_in[0];
    const float* ow = (const float*)d_in[2];   // orient_w (10,2): rows 0..7 = [cos, sin]
    float* out = (float*)d_out;

    dim3 grid(NCT, NRT, 8);
    sift_fused<<<grid, 256, 0, stream>>>(x, ow, out);
}

// Round 19
// 84.764 us; speedup vs baseline: 1.0724x; 1.0395x over previous
//
#include <hip/hip_runtime.h>
#include <math.h>

// Fused SIFT-like pipeline:
//   Sobel(3x3, pad1) -> project onto 8 orientations -> argmax -> magnitude
//   into winning bin -> depthwise 4x4 ones conv (pad2) => out (8,8,1025,1025)
//
// v19 == v15 (best passing, 84.0us): LDS stages pre-reduced (d,w) pairs
// (bit-identical Sobel trees), octant fast-path argmax with wave-uniform
// bit-exact fallback near bisectors, pair-sum ring, DPP horizontal sums,
// batch==XCD swizzle, launch_bounds(256,4).
// Final state after 18 rounds of single-variable experiments; see ledger.
//
// Block = 256 threads (4 waves), tile 61 out cols x 64 out rows; wave owns
// 16 rows. Lane l owns hist col j0-2+l; out col c = hist cols c..c+3 via
// DPP wave_shl:1 chains. launch_bounds(256,4).

#define TWC 61              // out cols per tile
#define WTH 16              // out rows per wave
#define WPB 4               // waves per block
#define BTH (WPB*WTH)       // 64 out rows per block
#define XR (BTH+5)          // 69 staged x rows
#define PLANE 1050625       // 1025*1025
#define NCT 17              // col tiles
#define NRT 17              // row tiles

// DPP wave_shl:1 (0x130): lane i <- lane i+1, zero-fill (== shfl_down 1)
__device__ __forceinline__ float wshl1(float v) {
    return __int_as_float(
        __builtin_amdgcn_update_dpp(0, __float_as_int(v), 0x130, 0xf, 0xf, true));
}

__global__ __launch_bounds__(256, 4)
void sift_fused(const float* __restrict__ x,
                const float* __restrict__ ow,
                float* __restrict__ out)
{
    // (d,w) float2 per (staged row, lane-col q): q in [0,64) <-> col j0-2+q
    __shared__ float sdw[XR * 128];        // 35,328 B

    const int tid  = threadIdx.x;
    const int lane = tid & 63;
    const int wv   = tid >> 6;

    // XCD-aware remap: batch == XCD (8 batches, 8 XCDs, bijective)
    const int flat = blockIdx.x + NCT * (blockIdx.y + NRT * blockIdx.z);
    const int bb = flat & 7;
    const int t  = flat >> 3;
    const int bx = t % NCT;
    const int by = t / NCT;
    const int j0 = bx * TWC;
    const int r0 = by * BTH;

    // ---- stage (d,w) rows: 16 groups of 4 cols per row ----
    const float* xb = x + (size_t)bb * 1024 * 1024;
    for (int s = tid; s < XR * 16; s += 256) {
        int r = s >> 4, g = s & 15;
        int grow = r0 - 3 + r;
        float4 o1, o2;
        if ((unsigned)grow < 1024u) {
            const float* rp = xb + ((size_t)(unsigned)grow << 10);
            int cb = j0 - 3 + 4 * g;       // x col of xv[0]
            float xv0, xv1, xv2, xv3, xv4, xv5;
            {
                int c;
                c = cb;     xv0 = ((unsigned)c < 1024u) ? rp[c] : 0.0f;
                c = cb + 1; xv1 = ((unsigned)c < 1024u) ? rp[c] : 0.0f;
                c = cb + 2; xv2 = ((unsigned)c < 1024u) ? rp[c] : 0.0f;
                c = cb + 3; xv3 = ((unsigned)c < 1024u) ? rp[c] : 0.0f;
                c = cb + 4; xv4 = ((unsigned)c < 1024u) ? rp[c] : 0.0f;
                c = cb + 5; xv5 = ((unsigned)c < 1024u) ? rp[c] : 0.0f;
            }
            // (d,w) for center cols cb+1..cb+4  (= hist cols j0-2+4g..+3)
            o1.x = xv2 - xv0;  o1.y = xv0 + 2.0f*xv1 + xv2;
            o1.z = xv3 - xv1;  o1.w = xv1 + 2.0f*xv2 + xv3;
            o2.x = xv4 - xv2;  o2.y = xv2 + 2.0f*xv3 + xv4;
            o2.z = xv5 - xv3;  o2.w = xv3 + 2.0f*xv4 + xv5;
        } else {
            o1.x=0.f;o1.y=0.f;o1.z=0.f;o1.w=0.f;
            o2.x=0.f;o2.y=0.f;o2.z=0.f;o2.w=0.f;
        }
        float* dst = &sdw[(r * 64 + 4 * g) * 2];
        *reinterpret_cast<float4*>(dst)     = o1;
        *reinterpret_cast<float4*>(dst + 4) = o2;
    }
    __syncthreads();

    const int rbase = r0 + WTH * wv;           // first output row of this wave
    if (rbase > 1024) return;                  // no barriers after this point

    // orientation weights (uniform loads; used by exact fallback path)
    float wcn[8], wsn[8];
    #pragma unroll
    for (int o = 0; o < 8; ++o) { wcn[o] = ow[2*o]; wsn[o] = ow[2*o+1]; }

    const int gcol = j0 - 2 + lane;            // hist column this lane owns
    const bool colok = (unsigned)gcol < 1024u;
    const int gj = j0 + lane;                  // output column this lane stores
    const bool canstore = (lane < TWC) && (gj <= 1024);

    // 8 uniform per-channel plane base pointers
    float* po[8];
    #pragma unroll
    for (int o = 0; o < 8; ++o) po[o] = out + (size_t)(bb * 8 + o) * PLANE;

    // (d,w) cursor: wave's first staged row, this lane's column
    const float2* pdw = reinterpret_cast<const float2*>(sdw)
                        + (WTH * wv) * 64 + lane;
    int hrow = rbase - 2;                      // global hist row of current step
    int orow = rbase;                          // global out row of next FIN
    int vo   = rbase * 1025 + gj;              // element offset within a plane

    // register state: d/w row rings (slot = xrow & 3), contrib ping-pong,
    // pair-sum ring (slot = histrow & 3)
    float dd0, dd1, dd2, dd3, ww0, ww1, ww2, ww3;
    float cA[8], cB[8], PP0[8], PP1[8], PP2[8], PP3[8];

#define XROWLOAD(DD, WW) { \
    float2 rdw_ = *pdw; pdw += 64; \
    DD = rdw_.x; WW = rdw_.y; \
}

// One hist row: load (d,w) row j+2 -> (DB,WB); Sobel from rings; magnitude;
// argmax: octant fast path, wave-uniform fallback to bit-exact
// projection+tournament near bisectors; one-hot contrib CC;
// pair sum PC = CP + CC; optional FIN of out row j-3.
#define HSTEP(DT, DM, DB, WT, WB, CP, CC, PR, PC, DOP, DOFIN) { \
    XROWLOAD(DB, WB) \
    float gx = DT + 2.0f*DM + DB; \
    float gy = WB - WT; \
    float msq = gx*gx + gy*gy; \
    float m = (colok && (unsigned)hrow < 1024u) \
                ? __builtin_amdgcn_sqrtf(msq) : 0.0f; \
    hrow++; \
    float ax_ = fabsf(gx), ay_ = fabsf(gy); \
    bool risky_ = fminf(fminf(ax_, ay_), fabsf(ay_ - ax_)) \
                    < 6.103515625e-5f * (ax_ + ay_); \
    int idx; \
    if (__any(risky_)) { \
        float pj0 = gx*wcn[0] + gy*wsn[0]; \
        float pj1 = gx*wcn[1] + gy*wsn[1]; \
        float pj2 = gx*wcn[2] + gy*wsn[2]; \
        float pj3 = gx*wcn[3] + gy*wsn[3]; \
        float pj4 = gx*wcn[4] + gy*wsn[4]; \
        float pj5 = gx*wcn[5] + gy*wsn[5]; \
        float pj6 = gx*wcn[6] + gy*wsn[6]; \
        float pj7 = gx*wcn[7] + gy*wsn[7]; \
        bool g01 = pj1 > pj0; float b01 = g01 ? pj1 : pj0; int i01 = g01 ? 1 : 0; \
        bool g23 = pj3 > pj2; float b23 = g23 ? pj3 : pj2; int i23 = g23 ? 3 : 2; \
        bool g45 = pj5 > pj4; float b45 = g45 ? pj5 : pj4; int i45 = g45 ? 5 : 4; \
        bool g67 = pj7 > pj6; float b67 = g67 ? pj7 : pj6; int i67 = g67 ? 7 : 6; \
        bool gA = b23 > b01; float bA = gA ? b23 : b01; int iA = gA ? i23 : i01; \
        bool gB = b67 > b45; float bB = gB ? b67 : b45; int iB = gB ? i67 : i45; \
        idx = (bB > bA) ? iB : iA; \
    } else { \
        bool a_ = gy < 0.0f, b_ = gx < 0.0f; \
        int c_ = (ay_ >= ax_) ? 1 : 0; \
        idx = b_ ? (a_ ? (4 + c_) : (3 - c_)) \
                 : (a_ ? (7 - c_) : c_); \
    } \
    _Pragma("unroll") \
    for (int o = 0; o < 8; ++o) CC[o] = (idx == o) ? m : 0.0f; \
    if (DOP) { \
        _Pragma("unroll") \
        for (int o = 0; o < 8; ++o) PC[o] = CP[o] + CC[o]; \
    } \
    if (DOFIN) { \
        bool ok = canstore && (orow <= 1024); \
        _Pragma("unroll") \
        for (int o = 0; o < 8; ++o) { \
            float v = PR[o] + PC[o]; \
            v += wshl1(v);                 /* + lane l+1            */ \
            v += wshl1(wshl1(v));          /* + lanes l+2, l+3      */ \
            if (ok) po[o][vo] = v; \
        } \
        vo += 1025; orow++; \
    } \
}

    // prologue: (d,w) rows 0,1 then hist rows j=0..2 (no FIN yet)
    XROWLOAD(dd0, ww0)
    XROWLOAD(dd1, ww1)
    HSTEP(dd0, dd1, dd2, ww0, ww2, cA, cB, PP0, PP0, 0, 0)   // j=0 (P_0 unused)
    HSTEP(dd1, dd2, dd3, ww1, ww3, cB, cA, PP0, PP1, 1, 0)   // j=1
    HSTEP(dd2, dd3, dd0, ww2, ww0, cA, cB, PP0, PP2, 1, 0)   // j=2

    // steady state: j = 3..18, FIN t = j-3 = 0..15
    #pragma unroll 1
    for (int it = 0; it < 4; ++it) {
        HSTEP(dd3, dd0, dd1, ww3, ww1, cB, cA, PP1, PP3, 1, 1)   // j%4==3
        HSTEP(dd0, dd1, dd2, ww0, ww2, cA, cB, PP2, PP0, 1, 1)   // j%4==0
        HSTEP(dd1, dd2, dd3, ww1, ww3, cB, cA, PP3, PP1, 1, 1)   // j%4==1
        HSTEP(dd2, dd3, dd0, ww2, ww0, cA, cB, PP0, PP2, 1, 1)   // j%4==2
    }

#undef HSTEP
#undef XROWLOAD
}

extern "C" void kernel_launch(void* const* d_in, const int* in_sizes, int n_in,
                              void* d_out, int out_size, void* d_ws, size_t ws_size,
                              hipStream_t stream)
{
    (void)in_sizes; (void)n_in; (void)d_ws; (void)ws_size; (void)out_size;
    const float* x  = (const float*)d_in[0];
    const float* ow = (const float*)d_in[2];   // orient_w (10,2): rows 0..7 = [cos, sin]
    float* out = (float*)d_out;

    dim3 grid(NCT, NRT, 8);
    sift_fused<<<grid, 256, 0, stream>>>(x, ow, out);
}